// Round 1
// baseline (426.910 us; speedup 1.0000x reference)
//
#include <hip/hip_runtime.h>
#include <hip/hip_bf16.h>

// ModulationConvBlock: per-sample modulated/demodulated 3x3 conv.
// fp32 in/out, bf16 MFMA internally. B=8, IN_C=OUT_C=256, H=W=128, K=3.
//
// Round-6 restructure:
//   k_conv: 24-stage (ky,icc) software pipeline, double-buffered LDS,
//           all 3 kx taps of W staged per stage (Wl row = 96+8 pad),
//           T14 split: global loads issued a full stage ahead, LDS writes
//           after the MFMAs, ONE __syncthreads per stage (was ~7).
//   k_transpose: float4 loads (16B/lane) + ushort4 stores (8B/lane).
//
// ws layout: Wt 9.00 MiB | norm2 8 KiB | Xt bc*8 MiB

typedef __attribute__((ext_vector_type(8))) short short8;
typedef __attribute__((ext_vector_type(4))) float floatx4;
typedef __attribute__((ext_vector_type(4))) unsigned short ushort4_t;
typedef __bf16 bf16x8 __attribute__((ext_vector_type(8)));

#define B_    8
#define IC_   256
#define OC_   256
#define HW_   128
#define PIX_  (HW_*HW_)
#define RTOT  2304                  // 9*256, k-order: tap-major, ic-minor
#define WSCALE (1.0f/48.0f)         // 1/sqrt(3*3*256)
#define STRX  40                    // Xl row stride (elems); 80B, 16B-aligned
#define STRW  104                   // Wl row stride (elems): 3*32 + 8 pad; 208B, 16B-aligned

static __device__ __forceinline__ floatx4 mfma_bf16(short8 a, short8 b, floatx4 c) {
  return __builtin_amdgcn_mfma_f32_16x16x32_bf16(
      __builtin_bit_cast(bf16x8, a), __builtin_bit_cast(bf16x8, b), c, 0, 0, 0);
}

static __device__ __forceinline__ unsigned short f2bf(float f) {
  unsigned int u = __builtin_bit_cast(unsigned int, f);
  return (unsigned short)(u >> 16) + (unsigned short)((u >> 15) & 1u);
}

// ---------------- Z: zero norm2 ----------------
__global__ __launch_bounds__(256) void k_zero(float* __restrict__ p, int n) {
  int i = blockIdx.x * 256 + threadIdx.x;
  if (i < n) p[i] = 0.f;
}

// ---------------- K0: NCHW fp32 -> NHWC bf16 transpose (chunk of bc batches) ------
// 64px x 64ic tile. Read: float4 (4 px) per lane. Write: ushort4 (4 ic) per lane.
__global__ __launch_bounds__(256) void k_transpose(const float* __restrict__ x,
                                                   unsigned short* __restrict__ Xt,
                                                   int b0) {
  __shared__ unsigned short t[64][66];                    // [ic_local][px_local], pad 66
  const int tid = threadIdx.x;
  const int p0 = blockIdx.x * 64, ic0 = blockIdx.y * 64, bz = blockIdx.z;
  const float* xb = x + (size_t)(b0 + bz) * IC_ * PIX_;
  unsigned short* xtb = Xt + (size_t)bz * PIX_ * IC_;     // chunk-local

  const int c2 = tid & 15, r2 = tid >> 4;                 // c2: px/4 group, r2: ic row base
#pragma unroll
  for (int jr = 0; jr < 4; ++jr) {
    const int row = r2 + jr * 16;                         // ic_local
    floatx4 f = *(const floatx4*)(&xb[(size_t)(ic0 + row) * PIX_ + p0 + 4 * c2]);
    t[row][4 * c2 + 0] = f2bf(f[0]);
    t[row][4 * c2 + 1] = f2bf(f[1]);
    t[row][4 * c2 + 2] = f2bf(f[2]);
    t[row][4 * c2 + 3] = f2bf(f[3]);
  }
  __syncthreads();
#pragma unroll
  for (int jj = 0; jj < 4; ++jj) {
    const int px = r2 + jj * 16;                          // wait: r2 in 0..15 -> px 0..63
    ushort4_t v = { t[4 * c2 + 0][px], t[4 * c2 + 1][px],
                    t[4 * c2 + 2][px], t[4 * c2 + 3][px] };
    *(ushort4_t*)(&xtb[(size_t)(p0 + px) * IC_ + ic0 + 4 * c2]) = v;   // 8B store
  }
}

// ---------------- A1: demod norms (fp32) ----------------
__global__ __launch_bounds__(256) void k_norm(const float* __restrict__ Wraw,
                                              const float* __restrict__ code,
                                              float* __restrict__ norm2) {
  const int tap = blockIdx.x % 9, b = blockIdx.x / 9;
  const int oc = threadIdx.x;
  __shared__ float cs[IC_];
  cs[oc] = code[b * IC_ + oc];
  __syncthreads();
  float s = 0.f;
#pragma unroll 8
  for (int ic = 0; ic < IC_; ++ic) {
    float v = Wraw[(size_t)(tap * IC_ + ic) * OC_ + oc] * cs[ic];
    s += v * v;
  }
  atomicAdd(&norm2[b * OC_ + oc], s * (WSCALE * WSCALE));
}

// ---------------- A2: write modulated+demodulated weights (bf16) ----------------
__global__ __launch_bounds__(256) void k_modw(const float* __restrict__ Wraw,
                                              const float* __restrict__ code,
                                              const float* __restrict__ norm2,
                                              unsigned short* __restrict__ Wt) {
  const int idx = blockIdx.x * 256 + threadIdx.x;   // idx = ((b*256 + oc)*2304 + r)
  const int r  = idx % RTOT;
  const int t2 = idx / RTOT;
  const int oc = t2 & 255;
  const int b  = t2 >> 8;
  const int ic = r & 255;
  const float w  = Wraw[(size_t)r * OC_ + oc];
  const float cd = code[b * IC_ + ic];
  const float rn = rsqrtf(norm2[b * OC_ + oc] + 1e-8f);
  Wt[idx] = f2bf(w * cd * WSCALE * rn);
}

// ---------------- K3: implicit-GEMM conv, pipelined (chunk of bc batches) ---------
// Block = 128oc x 128px (one image row). Stages s = 0..NS-1, stage = (iy, icc):
//   iy = lo + (s>>3), icc = s&7; per stage: W tile 128x(3x32), X tile 128x32.
// Pipeline: CLOAD(s+1) -> 48 MFMA on buf(s&1) -> DSW into buf(s&1 ^ 1) -> barrier.
__global__ __launch_bounds__(256, 2) void k_conv(const unsigned short* __restrict__ Xt,
                                                 const unsigned short* __restrict__ Wt,
                                                 const float* __restrict__ bias,
                                                 float* __restrict__ out,
                                                 int b0) {
  __shared__ __align__(16) unsigned short Wl[2][128 * STRW];   // 53.2 KiB
  __shared__ __align__(16) unsigned short Xl[2][130 * STRX];   // 20.8 KiB

  const int tid  = threadIdx.x;
  const int lane = tid & 63;
  const int wv   = tid >> 6;          // wave id 0..3
  const int wm   = wv & 1;            // oc-half of the 128x128 tile
  const int wn   = wv >> 1;           // px-half
  const int l15  = lane & 15;
  const int k0   = (lane >> 4) * 8;   // frag k-offset (elements)

  const int py = blockIdx.x, ot = blockIdx.y, bz = blockIdx.z;
  const int b  = b0 + bz;

  const unsigned short* Wtp = Wt + (size_t)(b * OC_ + ot * 128) * RTOT;
  const unsigned short* Xtp = Xt + (size_t)bz * PIX_ * IC_;   // chunk-local

  // staging thread mapping
  const int xc   = 1 + (tid >> 1);    // Xl column (px+1)
  const int xh   = tid & 1;           // 16-elem half
  const int wocr = tid >> 1;          // Wl row (oc_local)

  const int lo = (py > 0) ? py - 1 : 0;
  const int hi = (py < HW_ - 1) ? py + 1 : HW_ - 1;
  const int NS = (hi - lo + 1) * 8;   // 16 or 24, block-uniform

  const floatx4 zz = {0.f, 0.f, 0.f, 0.f};
  floatx4 acc[4][4];
#pragma unroll
  for (int i = 0; i < 4; ++i)
#pragma unroll
    for (int j = 0; j < 4; ++j) acc[i][j] = zz;

  // zero the padding columns (px=-1 and px=128) of BOTH buffers; never rewritten
  if (tid < 128) {
    const int bi = tid >> 6, rr = tid & 63;
    const int c = (rr < 32) ? 0 : 129;
    Xl[bi][c * STRX + (rr & 31)] = 0;
  }

  short8 xr0, xr1, wr0, wr1, wr2, wr3, wr4, wr5;

#define CLOAD(s_) do {                                                           \
    const int iy_   = lo + ((s_) >> 3);                                          \
    const int icc_  = (s_) & 7;                                                  \
    const int tapb_ = (iy_ - py + 1) * 3;                                        \
    const unsigned short* xs_ =                                                  \
        Xtp + (size_t)(iy_ * HW_ + xc - 1) * IC_ + icc_ * 32 + xh * 16;          \
    xr0 = *(const short8*)(xs_);                                                 \
    xr1 = *(const short8*)(xs_ + 8);                                             \
    const unsigned short* ws_ =                                                  \
        Wtp + (size_t)wocr * RTOT + (size_t)tapb_ * IC_ + icc_ * 32 + xh * 16;   \
    wr0 = *(const short8*)(ws_);                                                 \
    wr1 = *(const short8*)(ws_ + 8);                                             \
    wr2 = *(const short8*)(ws_ + IC_);                                           \
    wr3 = *(const short8*)(ws_ + IC_ + 8);                                       \
    wr4 = *(const short8*)(ws_ + 2 * IC_);                                       \
    wr5 = *(const short8*)(ws_ + 2 * IC_ + 8);                                   \
  } while (0)

#define DSW(b_) do {                                                             \
    unsigned short* xd_ = &Xl[b_][xc * STRX + xh * 16];                          \
    *(short8*)(xd_)     = xr0;                                                   \
    *(short8*)(xd_ + 8) = xr1;                                                   \
    unsigned short* wd_ = &Wl[b_][wocr * STRW + xh * 16];                        \
    *(short8*)(wd_)      = wr0;                                                  \
    *(short8*)(wd_ + 8)  = wr1;                                                  \
    *(short8*)(wd_ + 32) = wr2;                                                  \
    *(short8*)(wd_ + 40) = wr3;                                                  \
    *(short8*)(wd_ + 64) = wr4;                                                  \
    *(short8*)(wd_ + 72) = wr5;                                                  \
  } while (0)

  // prologue: stage 0 into buf 0
  CLOAD(0);
  DSW(0);
  __syncthreads();

  for (int s = 0; s < NS; ++s) {
    const int nb = s & 1;
    if (s + 1 < NS) CLOAD(s + 1);     // issue next-stage global loads (hidden under MFMAs)

#pragma unroll
    for (int kx = 0; kx < 3; ++kx) {
      short8 af[4], bfr[4];
#pragma unroll
      for (int i = 0; i < 4; ++i)
        af[i] = *(const short8*)(&Wl[nb][(wm * 64 + i * 16 + l15) * STRW + kx * 32 + k0]);
#pragma unroll
      for (int j = 0; j < 4; ++j)
        bfr[j] = *(const short8*)(&Xl[nb][(wn * 64 + j * 16 + l15 + kx) * STRX + k0]);
#pragma unroll
      for (int i = 0; i < 4; ++i)
#pragma unroll
        for (int j = 0; j < 4; ++j)
          acc[i][j] = mfma_bf16(af[i], bfr[j], acc[i][j]);
    }

    if (s + 1 < NS) DSW(nb ^ 1);      // write-late into the other buffer (vmcnt waits here)
    __syncthreads();                  // ONE barrier per stage
  }

#undef CLOAD
#undef DSW

  // epilogue: bias + LeakyReLU(0.2)*sqrt(2); C/D: col=lane&15 (px), row=(lane>>4)*4+p (oc)
  const int row0 = (lane >> 4) * 4;
#pragma unroll
  for (int i = 0; i < 4; ++i) {
#pragma unroll
    for (int p = 0; p < 4; ++p) {
      const int oc = ot * 128 + wm * 64 + i * 16 + row0 + p;
      const float bvf = bias[oc];
#pragma unroll
      for (int j = 0; j < 4; ++j) {
        const int px = wn * 64 + j * 16 + l15;
        float v = acc[i][j][p] + bvf;
        v = (v >= 0.f ? v : 0.2f * v) * 1.41421356237f;
        out[((size_t)(b * OC_ + oc) * HW_ + py) * HW_ + px] = v;   // fp32 store
      }
    }
  }
}

extern "C" void kernel_launch(void* const* d_in, const int* in_sizes, int n_in,
                              void* d_out, int out_size, void* d_ws, size_t ws_size,
                              hipStream_t stream) {
  const float* x    = (const float*)d_in[0];   // fp32 [8,256,128,128]
  const float* code = (const float*)d_in[1];   // fp32 [8,256]
  const float* wgt  = (const float*)d_in[2];   // fp32 [256,256,3,3] flat
  const float* bias = (const float*)d_in[3];   // fp32 [256]

  const size_t WT_BYTES = (size_t)B_ * OC_ * RTOT * 2;   // 9,437,184
  const size_t N2_BYTES = (size_t)B_ * OC_ * 4;          // 8,192
  const size_t XT_OFF   = WT_BYTES + N2_BYTES;           // 256B-aligned
  const size_t XB_BYTES = (size_t)PIX_ * IC_ * 2;        // 8 MiB per batch image

  unsigned short* Wt = (unsigned short*)d_ws;
  float* norm2       = (float*)((char*)d_ws + WT_BYTES);
  unsigned short* Xt = (unsigned short*)((char*)d_ws + XT_OFF);

  // Largest batch-chunk that fits ws_size (deterministic per ws_size -> graph-safe).
  int bc = 8;
  while (bc > 1 && XT_OFF + (size_t)bc * XB_BYTES > ws_size) bc >>= 1;

  k_zero<<<(B_ * OC_ + 255) / 256, 256, 0, stream>>>(norm2, B_ * OC_);
  k_norm<<<B_ * 9, 256, 0, stream>>>(wgt, code, norm2);
  k_modw<<<(B_ * OC_ * RTOT) / 256, 256, 0, stream>>>(wgt, code, norm2, Wt);
  for (int b0 = 0; b0 < B_; b0 += bc) {
    k_transpose<<<dim3(PIX_ / 64, IC_ / 64, bc), 256, 0, stream>>>(x, Xt, b0);
    k_conv<<<dim3(HW_, 2, bc), 256, 0, stream>>>(Xt, Wt, bias, (float*)d_out, b0);
  }
}

// Round 2
// 424.825 us; speedup vs baseline: 1.0049x; 1.0049x over previous
//
#include <hip/hip_runtime.h>
#include <hip/hip_bf16.h>

// ModulationConvBlock: per-sample modulated/demodulated 3x3 conv.
// fp32 in/out, bf16 MFMA internally. B=8, IN_C=OUT_C=256, H=W=128, K=3.
//
// Round-7: LDS bank-conflict fix in k_conv (T2-style XOR swizzle, 64B rows),
//          s_setprio around MFMA cluster (T5), bijective XCD block swizzle (T1),
//          b64-vectorized LDS writes in k_transpose.
//
// ws layout: Wt 9.00 MiB | norm2 8 KiB | Xt bc*8 MiB

typedef __attribute__((ext_vector_type(8))) short short8;
typedef __attribute__((ext_vector_type(4))) float floatx4;
typedef __attribute__((ext_vector_type(4))) unsigned short ushort4_t;
typedef __bf16 bf16x8 __attribute__((ext_vector_type(8)));

#define B_    8
#define IC_   256
#define OC_   256
#define HW_   128
#define PIX_  (HW_*HW_)
#define RTOT  2304                  // 9*256, k-order: tap-major, ic-minor
#define WSCALE (1.0f/48.0f)         // 1/sqrt(3*3*256)

// XOR swizzle: 8-elem (16B) slot index within a 32-elem (64B) row, keyed on row
// bits 0..3. Even 8-position spread for frag reads (rows=base+l15) AND staging
// writes (rows=tid>>1, halves=tid&1). Bits 3..4 only -> b128 accesses stay intact.
#define SWZ(row) ((((row) ^ ((row) >> 2)) & 3) << 3)

static __device__ __forceinline__ floatx4 mfma_bf16(short8 a, short8 b, floatx4 c) {
  return __builtin_amdgcn_mfma_f32_16x16x32_bf16(
      __builtin_bit_cast(bf16x8, a), __builtin_bit_cast(bf16x8, b), c, 0, 0, 0);
}

static __device__ __forceinline__ unsigned short f2bf(float f) {
  unsigned int u = __builtin_bit_cast(unsigned int, f);
  return (unsigned short)(u >> 16) + (unsigned short)((u >> 15) & 1u);
}

// ---------------- Z: zero norm2 ----------------
__global__ __launch_bounds__(256) void k_zero(float* __restrict__ p, int n) {
  int i = blockIdx.x * 256 + threadIdx.x;
  if (i < n) p[i] = 0.f;
}

// ---------------- K0: NCHW fp32 -> NHWC bf16 transpose (chunk of bc batches) ------
// 64px x 64ic tile. Read: float4 (4 px). LDS write: 1x b64. Store: ushort4 (4 ic).
__global__ __launch_bounds__(256) void k_transpose(const float* __restrict__ x,
                                                   unsigned short* __restrict__ Xt,
                                                   int b0) {
  __shared__ unsigned short t[64][66];                    // [ic_local][px_local], pad 66
  const int tid = threadIdx.x;
  const int p0 = blockIdx.x * 64, ic0 = blockIdx.y * 64, bz = blockIdx.z;
  const float* xb = x + (size_t)(b0 + bz) * IC_ * PIX_;
  unsigned short* xtb = Xt + (size_t)bz * PIX_ * IC_;     // chunk-local

  const int c2 = tid & 15, r2 = tid >> 4;                 // c2: px/4 group, r2: ic row base
#pragma unroll
  for (int jr = 0; jr < 4; ++jr) {
    const int row = r2 + jr * 16;                         // ic_local
    floatx4 f = *(const floatx4*)(&xb[(size_t)(ic0 + row) * PIX_ + p0 + 4 * c2]);
    ushort4_t w = { f2bf(f[0]), f2bf(f[1]), f2bf(f[2]), f2bf(f[3]) };
    *(ushort4_t*)(&t[row][4 * c2]) = w;                   // single b64 LDS write
  }
  __syncthreads();
#pragma unroll
  for (int jj = 0; jj < 4; ++jj) {
    const int px = r2 + jj * 16;
    ushort4_t v = { t[4 * c2 + 0][px], t[4 * c2 + 1][px],
                    t[4 * c2 + 2][px], t[4 * c2 + 3][px] };
    *(ushort4_t*)(&xtb[(size_t)(p0 + px) * IC_ + ic0 + 4 * c2]) = v;   // 8B store
  }
}

// ---------------- A1: demod norms (fp32) ----------------
__global__ __launch_bounds__(256) void k_norm(const float* __restrict__ Wraw,
                                              const float* __restrict__ code,
                                              float* __restrict__ norm2) {
  const int tap = blockIdx.x % 9, b = blockIdx.x / 9;
  const int oc = threadIdx.x;
  __shared__ float cs[IC_];
  cs[oc] = code[b * IC_ + oc];
  __syncthreads();
  float s = 0.f;
#pragma unroll 8
  for (int ic = 0; ic < IC_; ++ic) {
    float v = Wraw[(size_t)(tap * IC_ + ic) * OC_ + oc] * cs[ic];
    s += v * v;
  }
  atomicAdd(&norm2[b * OC_ + oc], s * (WSCALE * WSCALE));
}

// ---------------- A2: write modulated+demodulated weights (bf16) ----------------
__global__ __launch_bounds__(256) void k_modw(const float* __restrict__ Wraw,
                                              const float* __restrict__ code,
                                              const float* __restrict__ norm2,
                                              unsigned short* __restrict__ Wt) {
  const int idx = blockIdx.x * 256 + threadIdx.x;   // idx = ((b*256 + oc)*2304 + r)
  const int r  = idx % RTOT;
  const int t2 = idx / RTOT;
  const int oc = t2 & 255;
  const int b  = t2 >> 8;
  const int ic = r & 255;
  const float w  = Wraw[(size_t)r * OC_ + oc];
  const float cd = code[b * IC_ + ic];
  const float rn = rsqrtf(norm2[b * OC_ + oc] + 1e-8f);
  Wt[idx] = f2bf(w * cd * WSCALE * rn);
}

// ---------------- K3: implicit-GEMM conv, pipelined (chunk of bc batches) ---------
// Block = 128oc x 128px (one image row). Stages s = 0..NS-1, stage = (iy, icc).
// LDS: per-tap W arrays + X, 64B rows with XOR swizzle -> bank-conflict-free.
// Pipeline: CLOAD(s+1) -> 48 MFMA (setprio) on buf(s&1) -> DSW into buf(s&1^1) -> barrier.
__global__ __launch_bounds__(256, 2) void k_conv(const unsigned short* __restrict__ Xt,
                                                 const unsigned short* __restrict__ Wt,
                                                 const float* __restrict__ bias,
                                                 float* __restrict__ out,
                                                 int b0) {
  __shared__ __align__(16) unsigned short Wl[2][3][128 * 32];   // 48 KiB
  __shared__ __align__(16) unsigned short Xl[2][130 * 32];      // 16.25 KiB

  const int tid  = threadIdx.x;
  const int lane = tid & 63;
  const int wv   = tid >> 6;          // wave id 0..3
  const int wm   = wv & 1;            // oc-half of the 128x128 tile
  const int wn   = wv >> 1;           // px-half
  const int l15  = lane & 15;
  const int k0   = (lane >> 4) * 8;   // frag k-offset (elements)

  // T1: bijective XCD-chunk block swizzle (nwg = 256*bc, always %8==0)
  const int nwg  = (int)(gridDim.x * gridDim.y * gridDim.z);
  const int q    = nwg >> 3;
  const int flat = (int)(blockIdx.x + gridDim.x * (blockIdx.y + gridDim.y * blockIdx.z));
  const int nf   = (flat & 7) * q + (flat >> 3);
  const int py = nf & 127, ot = (nf >> 7) & 1, bz = nf >> 8;
  const int b  = b0 + bz;

  const unsigned short* Wtp = Wt + (size_t)(b * OC_ + ot * 128) * RTOT;
  const unsigned short* Xtp = Xt + (size_t)bz * PIX_ * IC_;   // chunk-local

  // staging thread mapping
  const int xc   = 1 + (tid >> 1);    // Xl row (px+1), 1..128
  const int xh   = tid & 1;           // 16-elem half
  const int wocr = tid >> 1;          // Wl row (oc_local)
  const int sST  = SWZ(wocr);         // staging swizzle (same row bits for W and X rows-1? no: per-row)
  const int sXC  = SWZ(xc);

  // read-side swizzles: row bits 0..3 of (l15 [+kx]) only (16-aligned bases drop out)
  const int sA  = SWZ(l15);
  const int sB0 = SWZ(l15 + 0), sB1 = SWZ(l15 + 1), sB2 = SWZ(l15 + 2);

  const int lo = (py > 0) ? py - 1 : 0;
  const int hi = (py < HW_ - 1) ? py + 1 : HW_ - 1;
  const int NS = (hi - lo + 1) * 8;   // 16 or 24, block-uniform

  const floatx4 zz = {0.f, 0.f, 0.f, 0.f};
  floatx4 acc[4][4];
#pragma unroll
  for (int i = 0; i < 4; ++i)
#pragma unroll
    for (int j = 0; j < 4; ++j) acc[i][j] = zz;

  // zero padding rows (px=-1 -> row 0, px=128 -> row 129) of BOTH buffers, fully
  if (tid < 128) {
    const int bi = tid >> 6, rr = tid & 63;
    const int r = (rr < 32) ? 0 : 129;
    Xl[bi][r * 32 + (rr & 31)] = 0;
  }

  short8 xr0, xr1, wr0, wr1, wr2, wr3, wr4, wr5;

#define CLOAD(s_) do {                                                           \
    const int iy_   = lo + ((s_) >> 3);                                          \
    const int icc_  = (s_) & 7;                                                  \
    const int tapb_ = (iy_ - py + 1) * 3;                                        \
    const unsigned short* xs_ =                                                  \
        Xtp + (size_t)(iy_ * HW_ + xc - 1) * IC_ + icc_ * 32 + xh * 16;          \
    xr0 = *(const short8*)(xs_);                                                 \
    xr1 = *(const short8*)(xs_ + 8);                                             \
    const unsigned short* ws_ =                                                  \
        Wtp + (size_t)wocr * RTOT + (size_t)tapb_ * IC_ + icc_ * 32 + xh * 16;   \
    wr0 = *(const short8*)(ws_);                                                 \
    wr1 = *(const short8*)(ws_ + 8);                                             \
    wr2 = *(const short8*)(ws_ + IC_);                                           \
    wr3 = *(const short8*)(ws_ + IC_ + 8);                                       \
    wr4 = *(const short8*)(ws_ + 2 * IC_);                                       \
    wr5 = *(const short8*)(ws_ + 2 * IC_ + 8);                                   \
  } while (0)

#define DSW(b_) do {                                                             \
    unsigned short* xd_ = &Xl[b_][xc * 32];                                      \
    *(short8*)(&xd_[(xh * 16)     ^ sXC]) = xr0;                                 \
    *(short8*)(&xd_[(xh * 16 + 8) ^ sXC]) = xr1;                                 \
    unsigned short* wd0_ = &Wl[b_][0][wocr * 32];                                \
    unsigned short* wd1_ = &Wl[b_][1][wocr * 32];                                \
    unsigned short* wd2_ = &Wl[b_][2][wocr * 32];                                \
    *(short8*)(&wd0_[(xh * 16)     ^ sST]) = wr0;                                \
    *(short8*)(&wd0_[(xh * 16 + 8) ^ sST]) = wr1;                                \
    *(short8*)(&wd1_[(xh * 16)     ^ sST]) = wr2;                                \
    *(short8*)(&wd1_[(xh * 16 + 8) ^ sST]) = wr3;                                \
    *(short8*)(&wd2_[(xh * 16)     ^ sST]) = wr4;                                \
    *(short8*)(&wd2_[(xh * 16 + 8) ^ sST]) = wr5;                                \
  } while (0)

  // prologue: stage 0 into buf 0
  CLOAD(0);
  DSW(0);
  __syncthreads();

  for (int s = 0; s < NS; ++s) {
    const int nb = s & 1;
    if (s + 1 < NS) CLOAD(s + 1);     // issue next-stage global loads (hidden under MFMAs)

    __builtin_amdgcn_s_setprio(1);
#pragma unroll
    for (int kx = 0; kx < 3; ++kx) {
      const int sB = (kx == 0) ? sB0 : (kx == 1) ? sB1 : sB2;
      short8 af[4], bfr[4];
#pragma unroll
      for (int i = 0; i < 4; ++i)
        af[i] = *(const short8*)(&Wl[nb][kx][(wm * 64 + i * 16 + l15) * 32 + (k0 ^ sA)]);
#pragma unroll
      for (int j = 0; j < 4; ++j)
        bfr[j] = *(const short8*)(&Xl[nb][(wn * 64 + j * 16 + l15 + kx) * 32 + (k0 ^ sB)]);
#pragma unroll
      for (int i = 0; i < 4; ++i)
#pragma unroll
        for (int j = 0; j < 4; ++j)
          acc[i][j] = mfma_bf16(af[i], bfr[j], acc[i][j]);
    }
    __builtin_amdgcn_s_setprio(0);

    if (s + 1 < NS) DSW(nb ^ 1);      // write-late into the other buffer
    __syncthreads();                  // ONE barrier per stage
  }

#undef CLOAD
#undef DSW

  // epilogue: bias + LeakyReLU(0.2)*sqrt(2); C/D: col=lane&15 (px), row=(lane>>4)*4+p (oc)
  const int row0 = (lane >> 4) * 4;
#pragma unroll
  for (int i = 0; i < 4; ++i) {
#pragma unroll
    for (int p = 0; p < 4; ++p) {
      const int oc = ot * 128 + wm * 64 + i * 16 + row0 + p;
      const float bvf = bias[oc];
#pragma unroll
      for (int j = 0; j < 4; ++j) {
        const int px = wn * 64 + j * 16 + l15;
        float v = acc[i][j][p] + bvf;
        v = (v >= 0.f ? v : 0.2f * v) * 1.41421356237f;
        out[((size_t)(b * OC_ + oc) * HW_ + py) * HW_ + px] = v;   // fp32 store
      }
    }
  }
}

extern "C" void kernel_launch(void* const* d_in, const int* in_sizes, int n_in,
                              void* d_out, int out_size, void* d_ws, size_t ws_size,
                              hipStream_t stream) {
  const float* x    = (const float*)d_in[0];   // fp32 [8,256,128,128]
  const float* code = (const float*)d_in[1];   // fp32 [8,256]
  const float* wgt  = (const float*)d_in[2];   // fp32 [256,256,3,3] flat
  const float* bias = (const float*)d_in[3];   // fp32 [256]

  const size_t WT_BYTES = (size_t)B_ * OC_ * RTOT * 2;   // 9,437,184
  const size_t N2_BYTES = (size_t)B_ * OC_ * 4;          // 8,192
  const size_t XT_OFF   = WT_BYTES + N2_BYTES;           // 256B-aligned
  const size_t XB_BYTES = (size_t)PIX_ * IC_ * 2;        // 8 MiB per batch image

  unsigned short* Wt = (unsigned short*)d_ws;
  float* norm2       = (float*)((char*)d_ws + WT_BYTES);
  unsigned short* Xt = (unsigned short*)((char*)d_ws + XT_OFF);

  // Largest batch-chunk that fits ws_size (deterministic per ws_size -> graph-safe).
  int bc = 8;
  while (bc > 1 && XT_OFF + (size_t)bc * XB_BYTES > ws_size) bc >>= 1;

  k_zero<<<(B_ * OC_ + 255) / 256, 256, 0, stream>>>(norm2, B_ * OC_);
  k_norm<<<B_ * 9, 256, 0, stream>>>(wgt, code, norm2);
  k_modw<<<(B_ * OC_ * RTOT) / 256, 256, 0, stream>>>(wgt, code, norm2, Wt);
  for (int b0 = 0; b0 < B_; b0 += bc) {
    k_transpose<<<dim3(PIX_ / 64, IC_ / 64, bc), 256, 0, stream>>>(x, Xt, b0);
    k_conv<<<dim3(HW_, 2, bc), 256, 0, stream>>>(Xt, Wt, bias, (float*)d_out, b0);
  }
}